// Round 6
// baseline (304.935 us; speedup 1.0000x reference)
//
#include <hip/hip_runtime.h>
#include <stdint.h>

// out[b] = argmax_k cos(h_b, A_k), int32, first-index ties.
// prep: rn[k]=1/max(||A_k||,eps); a8/h8 = int8(round(x_norm * 127/0.26)) row-major.
// score: i8 MFMA 16x16x64 screen (exact int accum, fixed scale -> rank by raw
//        int dot); per-row top-3 per block -> cand[4096][32][3].
//        v6: v5 data plan (h fragments direct from global -- layout verified
//        on-harness in v3/v5; only A through LDS, double-buffered 2x16KB,
//        2-phase pipeline) with the two spill causes removed:
//        (1) #pragma unroll 1 on the chunk loop -- only ONE chunk's h-loads
//            (32 regs) live at a time; no cross-barrier load hoisting.
//        (2) inline-asm MFMA with "+a" accumulator constraint -- forces the
//            64 acc regs into AGPRs, off the arch side (arch ~105 < 128).
// refine: exact fp32 rescore of top-8 of 96 candidates per row.

#define DIM 512
#define B_ROWS 4096
#define K_ROWS 32768
#define BT 128
#define KT 128
#define NKT (K_ROWS / KT)    // 256
#define KSLOTS 32            // grid = 32*32 = 1024; exactly 8 k-tiles per block
#define QSCALE (127.0f / 0.26f)

typedef __attribute__((ext_vector_type(4))) float fx4;
typedef __attribute__((ext_vector_type(4))) int int4v;
typedef unsigned long long u64;

__device__ __forceinline__ uint32_t ford(float s) {
    uint32_t u = __float_as_uint(s);
    return u ^ ((uint32_t)((int32_t)u >> 31) | 0x80000000u);
}
__device__ __forceinline__ u64 umax64(u64 a, u64 b) { return a > b ? a : b; }
__device__ __forceinline__ u64 umin64(u64 a, u64 b) { return a < b ? a : b; }
__device__ __forceinline__ uint32_t umax32(uint32_t a, uint32_t b) { return a > b ? a : b; }
__device__ __forceinline__ uint32_t umin32(uint32_t a, uint32_t b) { return a < b ? a : b; }

__device__ __forceinline__ int q8(float x, float qs) {
    int v = __float2int_rn(x * qs);
    return v < -127 ? -127 : (v > 127 ? 127 : v);
}

// MFMA with accumulator pinned to AGPRs (keeps arch-VGPR pressure low).
__device__ __forceinline__ void mfma_i8_agpr(int4v& acc, int4v a, int4v b) {
    asm("v_mfma_i32_16x16x64_i8 %0, %1, %2, %0"
        : "+a"(acc) : "v"(a), "v"(b));
}

// Fused prep: one wave per row. Blocks 0..8191 -> A rows (rn + a8);
// blocks 8192..9215 -> h rows (h8). Row-major i8, 8 bytes/lane.
__global__ __launch_bounds__(256) void prep_kernel(const float* __restrict__ A,
                                                   const float* __restrict__ h,
                                                   char* __restrict__ a8,
                                                   char* __restrict__ h8,
                                                   float* __restrict__ rn) {
    const int lane = threadIdx.x & 63, wid = threadIdx.x >> 6;
    const bool isA = blockIdx.x < 8192;
    const int row = (isA ? blockIdx.x : blockIdx.x - 8192) * 4 + wid;
    const float* src = (isA ? A : h) + (size_t)row * DIM;
    char* dst = (isA ? a8 : h8) + (size_t)row * DIM;

    const fx4* p = (const fx4*)src;
    fx4 a = p[lane * 2], b = p[lane * 2 + 1];
    float ss = a[0]*a[0] + a[1]*a[1] + a[2]*a[2] + a[3]*a[3]
             + b[0]*b[0] + b[1]*b[1] + b[2]*b[2] + b[3]*b[3];
    #pragma unroll
    for (int off = 32; off > 0; off >>= 1) ss += __shfl_xor(ss, off, 64);
    float r = 1.0f / fmaxf(sqrtf(ss), 1e-8f);
    if (isA && lane == 0) rn[row] = r;

    float qs = r * QSCALE;
    int v0 = q8(a[0], qs), v1 = q8(a[1], qs), v2 = q8(a[2], qs), v3 = q8(a[3], qs);
    int v4 = q8(b[0], qs), v5 = q8(b[1], qs), v6 = q8(b[2], qs), v7 = q8(b[3], qs);
    uint32_t lo = (uint32_t)(v0 & 255) | ((uint32_t)(v1 & 255) << 8)
                | ((uint32_t)(v2 & 255) << 16) | ((uint32_t)(v3 & 255) << 24);
    uint32_t hi = (uint32_t)(v4 & 255) | ((uint32_t)(v5 & 255) << 8)
                | ((uint32_t)(v6 & 255) << 16) | ((uint32_t)(v7 & 255) << 24);
    *reinterpret_cast<uint2*>(dst + lane * 8) = make_uint2(lo, hi);
}

typedef __attribute__((address_space(3))) uint32_t lds_u32;
typedef __attribute__((address_space(1))) const uint32_t g_u32;

// h-direct pipelined screen. LDS = 2 x 16KB A chunk buffers = 32KB.
// Per chunk (#pragma unroll 1): load 8 h frags global->reg (L1/L2-hot) ->
// stage next A chunk (global_load_lds) -> A ds_reads -> 32 asm MFMA (acc in
// AGPR) -> (rank at k-tile end) -> single barrier (vmcnt drain under compute).
__global__ __launch_bounds__(256, 2) void score_kernel(
    const char* __restrict__ h8, const char* __restrict__ a8,
    u64* __restrict__ cand)
{
    // A buf b at smem + b*16384 [128 rows][128 B] swizzled.
    // epilogue union: u32 cl[128][33] (16.9 KB) fits in 32 KB.
    __shared__ __attribute__((aligned(16))) char smem[32768];

    const int t = threadIdx.x, lane = t & 63, wid = t >> 6;
    const int wm = wid >> 1, wn = wid & 1;
    const int lr = lane & 15, q = lane >> 4;
    const int btile = blockIdx.x >> 5, kslot = blockIdx.x & 31;
    const int b0 = btile * BT;

    const int srow = lane >> 3;           // row within 8-row staging group
    const int scol = (lane & 7) ^ srow;   // source granule (XOR swizzle)
    const int s7 = lr & 7;
    const int sw0 = (q ^ s7) * 16;        // K-half 0: logical granule q
    const int sw1 = ((4 + q) ^ s7) * 16;  // K-half 1: logical granule 4+q

    // per-lane h fragment base: h8[b0 + wm*64 + mi*16 + lr][dc*128 + kh*64 + q*16]
    const char* hbase = h8 + (size_t)(b0 + wm * 64 + lr) * DIM + q * 16;

    uint32_t v1[16], v2[16];   // per-thread top-2 per C-row, (ord&~63)|meta
    #pragma unroll
    for (int s = 0; s < 16; s++) { v1[s] = 0u; v2[s] = 0u; }

    // stage global A chunk cc (= it*4 + dc) into buffer buf.
    // 4 waves x 4 issues cover 16 granule-groups (8 rows x 128 B) = 16 KB.
    auto stageA = [&](int cc, int buf) {
        const int kt = kslot + (cc >> 2) * KSLOTS;
        const int dcc = cc & 3;
        const char* asrc = a8 + (size_t)kt * KT * DIM;
        char* ab = smem + buf * 16384;
        #pragma unroll
        for (int i = 0; i < 4; i++) {
            int issue = wid * 4 + i;
            size_t roff = (size_t)(issue * 8 + srow) * DIM + dcc * 128 + scol * 16;
            __builtin_amdgcn_global_load_lds((g_u32*)(asrc + roff),
                (lds_u32*)(ab + issue * 1024), 16, 0, 0);
        }
    };

    // prologue: A chunk 0 into buf 0, drain once.
    stageA(0, 0);
    __syncthreads();

    #pragma unroll 1
    for (int it = 0; it < 8; it++) {
        int4v acc[4][4];
        #pragma unroll
        for (int mi = 0; mi < 4; mi++)
            #pragma unroll
            for (int ni = 0; ni < 4; ni++)
                acc[mi][ni] = (int4v){0, 0, 0, 0};

        // NOT unrolled: caps live h-loads at one chunk's worth (32 regs) and
        // prevents cross-barrier global-load hoisting (the v5 spill cause).
        #pragma unroll 1
        for (int dc = 0; dc < 4; dc++) {
            const int c = it * 4 + dc;

            // h fragments for THIS chunk, direct from global (L1/L2-hot;
            // issued first so latency hides under stage-issue + ds_reads).
            int4v hreg[2][4];
            #pragma unroll
            for (int kh = 0; kh < 2; kh++)
                #pragma unroll
                for (int mi = 0; mi < 4; mi++)
                    hreg[kh][mi] = *reinterpret_cast<const int4v*>(
                        hbase + mi * (16 * DIM) + dc * 128 + kh * 64);

            // issue next A chunk's loads BEFORE compute (last chunk: none)
            if (c < 31) stageA(c + 1, (dc & 1) ^ 1);

            const char* ab = smem + (dc & 1) * 16384;

            // K-half 0: 4 A reads, 16 MFMAs (acc pinned to AGPR)
            int4v af0[4];
            #pragma unroll
            for (int ni = 0; ni < 4; ni++)
                af0[ni] = *reinterpret_cast<const int4v*>(
                    ab + (wn * 64 + ni * 16 + lr) * 128 + sw0);
            #pragma unroll
            for (int mi = 0; mi < 4; mi++)
                #pragma unroll
                for (int ni = 0; ni < 4; ni++)
                    mfma_i8_agpr(acc[mi][ni], hreg[0][mi], af0[ni]);

            // K-half 1
            int4v af1[4];
            #pragma unroll
            for (int ni = 0; ni < 4; ni++)
                af1[ni] = *reinterpret_cast<const int4v*>(
                    ab + (wn * 64 + ni * 16 + lr) * 128 + sw1);
            #pragma unroll
            for (int mi = 0; mi < 4; mi++)
                #pragma unroll
                for (int ni = 0; ni < 4; ni++)
                    mfma_i8_agpr(acc[mi][ni], hreg[1][mi], af1[ni]);

            // rank at k-tile end, BEFORE the barrier (register-only work,
            // extra cover for the just-issued next-k-tile loads).
            if (dc == 3) {
                const uint32_t metabase = (uint32_t)(it << 2);
                #pragma unroll
                for (int mi = 0; mi < 4; mi++)
                    #pragma unroll
                    for (int ni = 0; ni < 4; ni++) {
                        const uint32_t meta = metabase | (uint32_t)ni;
                        #pragma unroll
                        for (int r = 0; r < 4; r++) {
                            uint32_t ord = (uint32_t)acc[mi][ni][r] ^ 0x80000000u;
                            uint32_t pk = (ord & 0xFFFFFFC0u) | meta;
                            int s = mi * 4 + r;
                            uint32_t lo = umin32(v1[s], pk);
                            v1[s] = umax32(v1[s], pk);
                            v2[s] = umax32(v2[s], lo);
                        }
                    }
            }

            // single per-chunk sync: drains this chunk's staged loads
            // (vmcnt(0)) and guarantees all waves consumed buf (dc&1) before
            // it is restaged next chunk.
            __syncthreads();
        }
    }

    // block top-3 per row via u32 LDS (stride 33); k reconstructed from column
    uint32_t* cl = (uint32_t*)smem;
    u64 g1 = 0, g2 = 0, g3 = 0;
    for (int pass = 0; pass < 2; pass++) {
        __syncthreads();
        #pragma unroll
        for (int s = 0; s < 16; s++) {
            int mi = s >> 2, r = s & 3;
            int row_local = wm * 64 + mi * 16 + q * 4 + r;
            cl[row_local * 33 + wn * 16 + lr] = pass ? v2[s] : v1[s];
        }
        __syncthreads();
        if (t < BT) {
            #pragma unroll 4
            for (int j = 0; j < 32; j++) {
                uint32_t pv = cl[t * 33 + j];
                uint32_t meta = pv & 63u;
                int k = (kslot + (int)(meta >> 2) * KSLOTS) * KT
                      + (j >> 4) * 64 + (int)(meta & 3u) * 16 + (j & 15);
                u64 e = ((u64)(pv & 0xFFFFFFC0u) << 32) | (u64)(~(uint32_t)k);
                u64 t1 = umax64(g1, e), t2 = umin64(g1, e);
                g3 = umax64(g3, umin64(g2, t2));
                g2 = umax64(g2, t2);
                g1 = t1;
            }
        }
    }
    if (t < BT) {
        size_t base = ((size_t)(b0 + t) * KSLOTS + kslot) * 3;
        cand[base] = g1;
        cand[base + 1] = g2;
        cand[base + 2] = g3;
    }
}

// one wave per row: top-8 of 96 candidates, exact fp32 rescore, argmax.
__global__ __launch_bounds__(256) void refine_kernel(
    const float* __restrict__ h, const float* __restrict__ A,
    const float* __restrict__ rn, const u64* __restrict__ cand,
    int* __restrict__ out)
{
    const int t = threadIdx.x, lane = t & 63, wid = t >> 6;
    const int row = blockIdx.x * 4 + wid;
    const u64* cr = cand + (size_t)row * (KSLOTS * 3);
    u64 x0 = cr[lane];                                         // 64 entries
    u64 x1 = (lane < KSLOTS * 3 - 64) ? cr[64 + lane] : 0ULL;  // 32 entries

    u64 sel[8];
    #pragma unroll
    for (int j = 0; j < 8; j++) {
        u64 v = umax64(x0, x1);
        #pragma unroll
        for (int m = 32; m >= 1; m >>= 1) v = umax64(v, __shfl_xor(v, m, 64));
        sel[j] = v;
        if (x0 == v) x0 = 0;
        else if (x1 == v) x1 = 0;
    }

    const fx4* hp = reinterpret_cast<const fx4*>(h + (size_t)row * DIM);
    fx4 h0 = hp[lane * 2], h1 = hp[lane * 2 + 1];

    u64 best = 0;
    #pragma unroll
    for (int j = 0; j < 8; j++) {
        uint32_t kg = ~(uint32_t)sel[j];
        const fx4* ap = reinterpret_cast<const fx4*>(A + (size_t)kg * DIM);
        fx4 a0 = ap[lane * 2], a1 = ap[lane * 2 + 1];
        float s = h0[0]*a0[0] + h0[1]*a0[1] + h0[2]*a0[2] + h0[3]*a0[3]
                + h1[0]*a1[0] + h1[1]*a1[1] + h1[2]*a1[2] + h1[3]*a1[3];
        #pragma unroll
        for (int m = 32; m >= 1; m >>= 1) s += __shfl_xor(s, m, 64);
        s *= rn[kg];
        u64 pk = ((u64)ford(s) << 32) | (u64)(~kg);
        best = umax64(best, pk);
    }
    if (lane == 0) out[row] = (int)(~(uint32_t)best);
}

extern "C" void kernel_launch(void* const* d_in, const int* in_sizes, int n_in,
                              void* d_out, int out_size, void* d_ws, size_t ws_size,
                              hipStream_t stream) {
    const float* h = (const float*)d_in[0];   // [4096, 512]
    const float* A = (const float*)d_in[1];   // [32768, 512]
    int* out = (int*)d_out;                   // [4096] int32

    // ws: a8 (16MB) | h8 (2MB) | rn (128KB) | cand (3MB)
    char* w = (char*)d_ws;
    char* a8 = w;
    char* h8 = w + (size_t)K_ROWS * DIM;
    float* rn = (float*)(w + (size_t)(K_ROWS + B_ROWS) * DIM);
    u64* cand = (u64*)(w + (size_t)(K_ROWS + B_ROWS) * DIM
                         + (size_t)K_ROWS * sizeof(float));

    prep_kernel<<<8192 + 1024, 256, 0, stream>>>(A, h, a8, h8, rn);
    score_kernel<<<32 * KSLOTS, 256, 0, stream>>>(h8, a8, cand);
    refine_kernel<<<B_ROWS / 4, 256, 0, stream>>>(h, A, rn, cand, out);
}

// Round 8
// 262.306 us; speedup vs baseline: 1.1625x; 1.1625x over previous
//
#include <hip/hip_runtime.h>
#include <stdint.h>

// out[b] = argmax_k cos(h_b, A_k), int32, first-index ties.
// prep: rn[k]=1/max(||A_k||,eps); a8/h8 = int8(round(x_norm * 127/0.26)) row-major.
// score: i8 MFMA 16x16x64 screen (exact int accum, fixed scale -> rank by raw
//        int dot); per-row top-3 per block -> cand[4096][32][3].
//        v9: h PERSISTENT IN REGISTERS. 512 thr / 8 waves (2m x 4n), wave
//        tile 64x32 -> acc[4][2]=32 regs, hreg[4][2][4]=128 regs loaded ONCE
//        per block from global (layout harness-verified in v3/v5). Only A
//        streams through LDS (2x16KB dbuf, v2's proven granule swizzle +
//        2-phase pipeline). LDS port traffic per CU: 48MB -> ~17MB; h never
//        restaged or re-read. Reg total ~230 <= 256 @ 2 waves/SIMD (acc is
//        small, unlike the v3-v6 failures). All hreg indexing compile-time.
// refine: exact fp32 rescore of top-8 of 96 candidates per row (unchanged).

#define DIM 512
#define B_ROWS 4096
#define K_ROWS 32768
#define BT 128
#define KT 128
#define NKT (K_ROWS / KT)    // 256
#define KSLOTS 32            // grid = 32*32 = 1024; exactly 8 k-tiles per block
#define QSCALE (127.0f / 0.26f)

typedef __attribute__((ext_vector_type(4))) float fx4;
typedef __attribute__((ext_vector_type(4))) int int4v;
typedef unsigned long long u64;

__device__ __forceinline__ uint32_t ford(float s) {
    uint32_t u = __float_as_uint(s);
    return u ^ ((uint32_t)((int32_t)u >> 31) | 0x80000000u);
}
__device__ __forceinline__ u64 umax64(u64 a, u64 b) { return a > b ? a : b; }
__device__ __forceinline__ u64 umin64(u64 a, u64 b) { return a < b ? a : b; }
__device__ __forceinline__ uint32_t umax32(uint32_t a, uint32_t b) { return a > b ? a : b; }
__device__ __forceinline__ uint32_t umin32(uint32_t a, uint32_t b) { return a < b ? a : b; }

__device__ __forceinline__ int q8(float x, float qs) {
    int v = __float2int_rn(x * qs);
    return v < -127 ? -127 : (v > 127 ? 127 : v);
}

// Fused prep: one wave per row. Blocks 0..8191 -> A rows (rn + a8);
// blocks 8192..9215 -> h rows (h8). Row-major i8, 8 bytes/lane.
__global__ __launch_bounds__(256) void prep_kernel(const float* __restrict__ A,
                                                   const float* __restrict__ h,
                                                   char* __restrict__ a8,
                                                   char* __restrict__ h8,
                                                   float* __restrict__ rn) {
    const int lane = threadIdx.x & 63, wid = threadIdx.x >> 6;
    const bool isA = blockIdx.x < 8192;
    const int row = (isA ? blockIdx.x : blockIdx.x - 8192) * 4 + wid;
    const float* src = (isA ? A : h) + (size_t)row * DIM;
    char* dst = (isA ? a8 : h8) + (size_t)row * DIM;

    const fx4* p = (const fx4*)src;
    fx4 a = p[lane * 2], b = p[lane * 2 + 1];
    float ss = a[0]*a[0] + a[1]*a[1] + a[2]*a[2] + a[3]*a[3]
             + b[0]*b[0] + b[1]*b[1] + b[2]*b[2] + b[3]*b[3];
    #pragma unroll
    for (int off = 32; off > 0; off >>= 1) ss += __shfl_xor(ss, off, 64);
    float r = 1.0f / fmaxf(sqrtf(ss), 1e-8f);
    if (isA && lane == 0) rn[row] = r;

    float qs = r * QSCALE;
    int v0 = q8(a[0], qs), v1 = q8(a[1], qs), v2 = q8(a[2], qs), v3 = q8(a[3], qs);
    int v4 = q8(b[0], qs), v5 = q8(b[1], qs), v6 = q8(b[2], qs), v7 = q8(b[3], qs);
    uint32_t lo = (uint32_t)(v0 & 255) | ((uint32_t)(v1 & 255) << 8)
                | ((uint32_t)(v2 & 255) << 16) | ((uint32_t)(v3 & 255) << 24);
    uint32_t hi = (uint32_t)(v4 & 255) | ((uint32_t)(v5 & 255) << 8)
                | ((uint32_t)(v6 & 255) << 16) | ((uint32_t)(v7 & 255) << 24);
    *reinterpret_cast<uint2*>(dst + lane * 8) = make_uint2(lo, hi);
}

typedef __attribute__((address_space(3))) uint32_t lds_u32;
typedef __attribute__((address_space(1))) const uint32_t g_u32;

// h-in-register pipelined screen. 8 waves (2m x 4n), wave tile 64x32.
// LDS: A dbuf 2 x 16KB @ [0, 32768); epilogue u32 cl[128][65] (33280 B)
// overlays it after the main loop. hreg loaded once per block in prologue.
// Per phase: stage next A chunk -> 4 af ds_read_b128 -> 16 MFMA ->
// (rank at k-tile end) -> __syncthreads (drain covered by phase compute).
__global__ __launch_bounds__(512, 2) void score_kernel(
    const char* __restrict__ h8, const char* __restrict__ a8,
    u64* __restrict__ cand)
{
    __shared__ __attribute__((aligned(16))) char smem[33792];

    const int t = threadIdx.x, lane = t & 63, wid = t >> 6;
    const int wm = wid >> 2, wn = wid & 3;   // 2m x 4n wave grid
    const int lr = lane & 15, q = lane >> 4;
    const int btile = blockIdx.x >> 5, kslot = blockIdx.x & 31;
    const int b0 = btile * BT;

    const int srow = lane >> 3;           // row within 8-row staging group
    const int scol = (lane & 7) ^ srow;   // source granule (XOR swizzle)
    const int s7 = lr & 7;
    const int sw0 = (q ^ s7) * 16;        // K-half 0: logical granule q
    const int sw1 = ((4 + q) ^ s7) * 16;  // K-half 1: logical granule 4+q

    uint32_t v1[16], v2[16];   // per-thread top-2 per C-row, (ord&~63)|meta
    #pragma unroll
    for (int s = 0; s < 16; s++) { v1[s] = 0u; v2[s] = 0u; }

    // stage global A chunk cc (= it*4 + dc) into buffer buf.
    // 8 waves x 2 issues cover 16 granule-groups (8 rows x 128 B) = 16 KB.
    auto stageA = [&](int cc, int buf) {
        const int kt = kslot + (cc >> 2) * KSLOTS;
        const int dcc = cc & 3;
        const char* asrc = a8 + (size_t)(kt * KT) * DIM;
        char* ab = smem + buf * 16384;
        #pragma unroll
        for (int i = 0; i < 2; i++) {
            int issue = wid * 2 + i;
            size_t roff = (size_t)(issue * 8 + srow) * DIM + dcc * 128 + scol * 16;
            __builtin_amdgcn_global_load_lds((g_u32*)(asrc + roff),
                (lds_u32*)(ab + issue * 1024), 16, 0, 0);
        }
    };

    // prologue: A chunk 0 in flight, then persistent h fragments -> 128 VGPR.
    // Fragment layout harness-verified (v3/v5 absmax=0):
    // hreg[dc][kh][mi] = h8[b0+wm*64+mi*16+lr][dc*128 + kh*64 + q*16 ..+16]
    stageA(0, 0);

    int4v hreg[4][2][4];   // all indices compile-time constant (full unroll)
    {
        const char* hbase = h8 + (size_t)(b0 + wm * 64 + lr) * DIM + q * 16;
        #pragma unroll
        for (int dc = 0; dc < 4; dc++)
            #pragma unroll
            for (int kh = 0; kh < 2; kh++)
                #pragma unroll
                for (int mi = 0; mi < 4; mi++)
                    hreg[dc][kh][mi] = *reinterpret_cast<const int4v*>(
                        hbase + mi * (16 * DIM) + dc * 128 + kh * 64);
    }

    __syncthreads();   // drains A chunk-0 staging (and h loads)

    #pragma unroll 1
    for (int it = 0; it < 8; it++) {
        int4v acc[4][2];   // [mi][ni] -- 32 regs
        #pragma unroll
        for (int mi = 0; mi < 4; mi++)
            #pragma unroll
            for (int ni = 0; ni < 2; ni++)
                acc[mi][ni] = (int4v){0, 0, 0, 0};

        #pragma unroll
        for (int dc = 0; dc < 4; dc++) {
            const int c = it * 4 + dc;
            // issue next A chunk's loads BEFORE compute (last chunk: none)
            if (dc < 3 || it < 7) stageA(c + 1, (dc & 1) ^ 1);

            const char* ab = smem + (dc & 1) * 16384;

            int4v af0[2], af1[2];
            #pragma unroll
            for (int ni = 0; ni < 2; ni++) {
                const char* base = ab + (wn * 32 + ni * 16 + lr) * 128;
                af0[ni] = *reinterpret_cast<const int4v*>(base + sw0);
                af1[ni] = *reinterpret_cast<const int4v*>(base + sw1);
            }
            #pragma unroll
            for (int mi = 0; mi < 4; mi++)
                #pragma unroll
                for (int ni = 0; ni < 2; ni++) {
                    acc[mi][ni] = __builtin_amdgcn_mfma_i32_16x16x64_i8(
                        hreg[dc][0][mi], af0[ni], acc[mi][ni], 0, 0, 0);
                    acc[mi][ni] = __builtin_amdgcn_mfma_i32_16x16x64_i8(
                        hreg[dc][1][mi], af1[ni], acc[mi][ni], 0, 0, 0);
                }

            // rank at k-tile end, BEFORE the barrier (register-only work;
            // extra cover for the just-issued next-k-tile loads).
            if (dc == 3) {
                const uint32_t metabase = (uint32_t)(it << 1);
                #pragma unroll
                for (int mi = 0; mi < 4; mi++)
                    #pragma unroll
                    for (int ni = 0; ni < 2; ni++) {
                        const uint32_t meta = metabase | (uint32_t)ni;
                        #pragma unroll
                        for (int r = 0; r < 4; r++) {
                            uint32_t ord = (uint32_t)acc[mi][ni][r] ^ 0x80000000u;
                            uint32_t pk = (ord & 0xFFFFFFC0u) | meta;
                            int s = mi * 4 + r;
                            uint32_t lo = umin32(v1[s], pk);
                            v1[s] = umax32(v1[s], pk);
                            v2[s] = umax32(v2[s], lo);
                        }
                    }
            }

            // single per-chunk sync: drains this chunk's staged loads
            // (vmcnt(0), covered by the compute above) and guarantees all
            // waves consumed buf (dc&1) before it is restaged next chunk.
            __syncthreads();
        }
    }

    // block top-3 per row via u32 LDS cl[128][65]; k reconstructed from
    // column j = wn*16+lr (wn in [0,4)) and meta = (it<<1)|ni.
    uint32_t* cl = (uint32_t*)smem;
    u64 g1 = 0, g2 = 0, g3 = 0;
    for (int pass = 0; pass < 2; pass++) {
        __syncthreads();
        #pragma unroll
        for (int s = 0; s < 16; s++) {
            int mi = s >> 2, r = s & 3;
            int row_local = wm * 64 + mi * 16 + q * 4 + r;
            cl[row_local * 65 + wn * 16 + lr] = pass ? v2[s] : v1[s];
        }
        __syncthreads();
        if (t < BT) {
            #pragma unroll 4
            for (int j = 0; j < 64; j++) {
                uint32_t pv = cl[t * 65 + j];
                uint32_t meta = pv & 63u;
                int k = (kslot + (int)(meta >> 1) * KSLOTS) * KT
                      + (j >> 4) * 32 + (int)(meta & 1u) * 16 + (j & 15);
                u64 e = ((u64)(pv & 0xFFFFFFC0u) << 32) | (u64)(~(uint32_t)k);
                u64 t1 = umax64(g1, e), t2 = umin64(g1, e);
                g3 = umax64(g3, umin64(g2, t2));
                g2 = umax64(g2, t2);
                g1 = t1;
            }
        }
    }
    if (t < BT) {
        size_t base = ((size_t)(b0 + t) * KSLOTS + kslot) * 3;
        cand[base] = g1;
        cand[base + 1] = g2;
        cand[base + 2] = g3;
    }
}

// one wave per row: top-8 of 96 candidates, exact fp32 rescore, argmax.
__global__ __launch_bounds__(256) void refine_kernel(
    const float* __restrict__ h, const float* __restrict__ A,
    const float* __restrict__ rn, const u64* __restrict__ cand,
    int* __restrict__ out)
{
    const int t = threadIdx.x, lane = t & 63, wid = t >> 6;
    const int row = blockIdx.x * 4 + wid;
    const u64* cr = cand + (size_t)row * (KSLOTS * 3);
    u64 x0 = cr[lane];                                         // 64 entries
    u64 x1 = (lane < KSLOTS * 3 - 64) ? cr[64 + lane] : 0ULL;  // 32 entries

    u64 sel[8];
    #pragma unroll
    for (int j = 0; j < 8; j++) {
        u64 v = umax64(x0, x1);
        #pragma unroll
        for (int m = 32; m >= 1; m >>= 1) v = umax64(v, __shfl_xor(v, m, 64));
        sel[j] = v;
        if (x0 == v) x0 = 0;
        else if (x1 == v) x1 = 0;
    }

    const fx4* hp = reinterpret_cast<const fx4*>(h + (size_t)row * DIM);
    fx4 h0 = hp[lane * 2], h1 = hp[lane * 2 + 1];

    u64 best = 0;
    #pragma unroll
    for (int j = 0; j < 8; j++) {
        uint32_t kg = ~(uint32_t)sel[j];
        const fx4* ap = reinterpret_cast<const fx4*>(A + (size_t)kg * DIM);
        fx4 a0 = ap[lane * 2], a1 = ap[lane * 2 + 1];
        float s = h0[0]*a0[0] + h0[1]*a0[1] + h0[2]*a0[2] + h0[3]*a0[3]
                + h1[0]*a1[0] + h1[1]*a1[1] + h1[2]*a1[2] + h1[3]*a1[3];
        #pragma unroll
        for (int m = 32; m >= 1; m >>= 1) s += __shfl_xor(s, m, 64);
        s *= rn[kg];
        u64 pk = ((u64)ford(s) << 32) | (u64)(~kg);
        best = umax64(best, pk);
    }
    if (lane == 0) out[row] = (int)(~(uint32_t)best);
}

extern "C" void kernel_launch(void* const* d_in, const int* in_sizes, int n_in,
                              void* d_out, int out_size, void* d_ws, size_t ws_size,
                              hipStream_t stream) {
    const float* h = (const float*)d_in[0];   // [4096, 512]
    const float* A = (const float*)d_in[1];   // [32768, 512]
    int* out = (int*)d_out;                   // [4096] int32

    // ws: a8 (16MB) | h8 (2MB) | rn (128KB) | cand (3MB)
    char* w = (char*)d_ws;
    char* a8 = w;
    char* h8 = w + (size_t)K_ROWS * DIM;
    float* rn = (float*)(w + (size_t)(K_ROWS + B_ROWS) * DIM);
    u64* cand = (u64*)(w + (size_t)(K_ROWS + B_ROWS) * DIM
                         + (size_t)K_ROWS * sizeof(float));

    prep_kernel<<<8192 + 1024, 256, 0, stream>>>(A, h, a8, h8, rn);
    score_kernel<<<32 * KSLOTS, 512, 0, stream>>>(h8, a8, cand);
    refine_kernel<<<B_ROWS / 4, 256, 0, stream>>>(h, A, rn, cand, out);
}

// Round 9
// 194.406 us; speedup vs baseline: 1.5685x; 1.3493x over previous
//
#include <hip/hip_runtime.h>
#include <stdint.h>

// out[b] = argmax_k cos(h_b, A_k), int32, first-index ties.
// prep: rn[k]=1/max(||A_k||,eps); a8/h8 = int8(round(x_norm * 127/0.26)) row-major.
// score: i8 MFMA 16x16x64 screen (exact int accum, fixed scale -> rank by raw
//        int dot); per-row top-3 per block -> cand[4096][32][3].
//        v10 = v2 (verified 88.8us) + CORRECT two-barrier counted-vmcnt phase
//        (m201 discipline, fixes v7's race):
//          stage(c+1) -> vmcnt(8) [own batch-c done] -> s_barrier [ALL waves'
//          batch-c done => buf valid] -> ds_read+MFMA(+rank) -> lgkmcnt(0) ->
//          s_barrier [reads done => buf restageable].
//        Batch c+1 stays in flight across both barriers (a full phase of
//        cover) -- staging leaves the critical path. vmcnt is per-wave, so
//        each wave waits its OWN loads BEFORE the publishing barrier.
//        T5 setprio(1) around the MFMA cluster. Zero register delta vs v2.
// refine: exact fp32 rescore of top-8 of 96 candidates per row.

#define DIM 512
#define B_ROWS 4096
#define K_ROWS 32768
#define BT 128
#define KT 128
#define NKT (K_ROWS / KT)    // 256
#define KSLOTS 32            // grid = 32*32 = 1024; exactly 8 k-tiles per block
#define NCHUNK 4             // D chunks of 128 bytes (i8)
#define QSCALE (127.0f / 0.26f)

typedef __attribute__((ext_vector_type(4))) float fx4;
typedef __attribute__((ext_vector_type(4))) int int4v;
typedef unsigned long long u64;

__device__ __forceinline__ uint32_t ford(float s) {
    uint32_t u = __float_as_uint(s);
    return u ^ ((uint32_t)((int32_t)u >> 31) | 0x80000000u);
}
__device__ __forceinline__ u64 umax64(u64 a, u64 b) { return a > b ? a : b; }
__device__ __forceinline__ u64 umin64(u64 a, u64 b) { return a < b ? a : b; }
__device__ __forceinline__ uint32_t umax32(uint32_t a, uint32_t b) { return a > b ? a : b; }
__device__ __forceinline__ uint32_t umin32(uint32_t a, uint32_t b) { return a < b ? a : b; }

__device__ __forceinline__ int q8(float x, float qs) {
    int v = __float2int_rn(x * qs);
    return v < -127 ? -127 : (v > 127 ? 127 : v);
}

// Fused prep: one wave per row. Blocks 0..8191 -> A rows (rn + a8);
// blocks 8192..9215 -> h rows (h8). Row-major i8, 8 bytes/lane.
__global__ __launch_bounds__(256) void prep_kernel(const float* __restrict__ A,
                                                   const float* __restrict__ h,
                                                   char* __restrict__ a8,
                                                   char* __restrict__ h8,
                                                   float* __restrict__ rn) {
    const int lane = threadIdx.x & 63, wid = threadIdx.x >> 6;
    const bool isA = blockIdx.x < 8192;
    const int row = (isA ? blockIdx.x : blockIdx.x - 8192) * 4 + wid;
    const float* src = (isA ? A : h) + (size_t)row * DIM;
    char* dst = (isA ? a8 : h8) + (size_t)row * DIM;

    const fx4* p = (const fx4*)src;
    fx4 a = p[lane * 2], b = p[lane * 2 + 1];
    float ss = a[0]*a[0] + a[1]*a[1] + a[2]*a[2] + a[3]*a[3]
             + b[0]*b[0] + b[1]*b[1] + b[2]*b[2] + b[3]*b[3];
    #pragma unroll
    for (int off = 32; off > 0; off >>= 1) ss += __shfl_xor(ss, off, 64);
    float r = 1.0f / fmaxf(sqrtf(ss), 1e-8f);
    if (isA && lane == 0) rn[row] = r;

    float qs = r * QSCALE;
    int v0 = q8(a[0], qs), v1 = q8(a[1], qs), v2 = q8(a[2], qs), v3 = q8(a[3], qs);
    int v4 = q8(b[0], qs), v5 = q8(b[1], qs), v6 = q8(b[2], qs), v7 = q8(b[3], qs);
    uint32_t lo = (uint32_t)(v0 & 255) | ((uint32_t)(v1 & 255) << 8)
                | ((uint32_t)(v2 & 255) << 16) | ((uint32_t)(v3 & 255) << 24);
    uint32_t hi = (uint32_t)(v4 & 255) | ((uint32_t)(v5 & 255) << 8)
                | ((uint32_t)(v6 & 255) << 16) | ((uint32_t)(v7 & 255) << 24);
    *reinterpret_cast<uint2*>(dst + lane * 8) = make_uint2(lo, hi);
}

typedef __attribute__((address_space(3))) uint32_t lds_u32;
typedef __attribute__((address_space(1))) const uint32_t g_u32;

// 2-phase pipelined screen, two-barrier counted-vmcnt discipline.
// LDS = 2 x (hf 16KB + af 16KB) = 64KB -> 2 blocks/CU.
__global__ __launch_bounds__(256, 2) void score_kernel(
    const char* __restrict__ h8, const char* __restrict__ a8,
    u64* __restrict__ cand)
{
    // buf b at smem + b*32768: hf @ +0 [128 rows][128 B], af @ +16384.
    // epilogue union: u32 cl[128][33] (16.9 KB) over buf 0.
    __shared__ __attribute__((aligned(16))) char smem[65536];

    const int t = threadIdx.x, lane = t & 63, wid = t >> 6;
    const int wm = wid >> 1, wn = wid & 1;
    const int lr = lane & 15, q = lane >> 4;
    const int btile = blockIdx.x >> 5, kslot = blockIdx.x & 31;
    const int b0 = btile * BT;

    const int srow = lane >> 3;           // row within 8-row staging group
    const int scol = (lane & 7) ^ srow;   // source granule (XOR swizzle)
    const int s7 = lr & 7;
    const int sw0 = (q ^ s7) * 16;        // K-half 0: source granule q
    const int sw1 = ((4 + q) ^ s7) * 16;  // K-half 1: source granule 4+q

    const char* hsrc = h8 + (size_t)b0 * DIM;

    uint32_t v1[16], v2[16];   // per-thread top-2 per C-row, (ord&~63)|meta
    #pragma unroll
    for (int s = 0; s < 16; s++) { v1[s] = 0u; v2[s] = 0u; }

    // stage global chunk cc (= it*4 + dc) into buffer buf: 8 loads/wave.
    auto stage = [&](int cc, int buf) {
        const int kt = kslot + (cc >> 2) * KSLOTS;
        const int dcc = cc & 3;
        const char* asrc = a8 + (size_t)(kt * KT) * DIM;
        char* hb = smem + buf * 32768;
        char* ab = hb + 16384;
        #pragma unroll
        for (int i = 0; i < 4; i++) {
            int issue = wid * 4 + i;
            size_t roff = (size_t)(issue * 8 + srow) * DIM + dcc * 128 + scol * 16;
            __builtin_amdgcn_global_load_lds((g_u32*)(hsrc + roff),
                (lds_u32*)(hb + issue * 1024), 16, 0, 0);
            __builtin_amdgcn_global_load_lds((g_u32*)(asrc + roff),
                (lds_u32*)(ab + issue * 1024), 16, 0, 0);
        }
    };

    // prologue: chunk 0 in flight; phase 0's vmcnt+barrier publishes it.
    stage(0, 0);

    #pragma unroll 1
    for (int it = 0; it < 8; it++) {
        int4v acc[4][4];
        #pragma unroll
        for (int mi = 0; mi < 4; mi++)
            #pragma unroll
            for (int ni = 0; ni < 4; ni++)
                acc[mi][ni] = (int4v){0, 0, 0, 0};

        #pragma unroll
        for (int dc = 0; dc < 4; dc++) {
            const int c = it * 4 + dc;
            // issue next chunk's loads FIRST (last phase: none left)
            if (dc < 3 || it < 7) stage(c + 1, (dc & 1) ^ 1);

            // wait for THIS WAVE's batch-c loads (8 older than the 8 just
            // issued), THEN barrier: after it, ALL waves' batch-c loads are
            // complete -> buf (dc&1) fully staged. Batch c+1 stays in
            // flight across the barrier. Last phase: nothing newer -> 0.
            if (dc < 3 || it < 7) {
                asm volatile("s_waitcnt vmcnt(8)" ::: "memory");
            } else {
                asm volatile("s_waitcnt vmcnt(0)" ::: "memory");
            }
            __builtin_amdgcn_s_barrier();

            const char* hf = smem + (dc & 1) * 32768;
            const char* af = hf + 16384;

            int4v af0[4], af1[4];
            #pragma unroll
            for (int ni = 0; ni < 4; ni++) {
                const char* base = af + (wn * 64 + ni * 16 + lr) * 128;
                af0[ni] = *reinterpret_cast<const int4v*>(base + sw0);
                af1[ni] = *reinterpret_cast<const int4v*>(base + sw1);
            }
            __builtin_amdgcn_s_setprio(1);
            #pragma unroll
            for (int mi = 0; mi < 4; mi++) {
                const char* base = hf + (wm * 64 + mi * 16 + lr) * 128;
                int4v h0 = *reinterpret_cast<const int4v*>(base + sw0);
                int4v h1 = *reinterpret_cast<const int4v*>(base + sw1);
                #pragma unroll
                for (int ni = 0; ni < 4; ni++) {
                    acc[mi][ni] = __builtin_amdgcn_mfma_i32_16x16x64_i8(h0, af0[ni], acc[mi][ni], 0, 0, 0);
                    acc[mi][ni] = __builtin_amdgcn_mfma_i32_16x16x64_i8(h1, af1[ni], acc[mi][ni], 0, 0, 0);
                }
            }
            __builtin_amdgcn_s_setprio(0);

            // rank at k-tile end (register-only; extra cover for the
            // in-flight next-k-tile loads).
            if (dc == 3) {
                const uint32_t metabase = (uint32_t)(it << 2);
                #pragma unroll
                for (int mi = 0; mi < 4; mi++)
                    #pragma unroll
                    for (int ni = 0; ni < 4; ni++) {
                        const uint32_t meta = metabase | (uint32_t)ni;
                        #pragma unroll
                        for (int r = 0; r < 4; r++) {
                            uint32_t ord = (uint32_t)acc[mi][ni][r] ^ 0x80000000u;
                            uint32_t pk = (ord & 0xFFFFFFC0u) | meta;
                            int s = mi * 4 + r;
                            uint32_t lo = umin32(v1[s], pk);
                            v1[s] = umax32(v1[s], pk);
                            v2[s] = umax32(v2[s], lo);
                        }
                    }
            }

            // own LDS reads complete, then barrier: all waves' reads of
            // buf (dc&1) done -> it may be restaged next phase. The
            // in-flight batch c+1 crosses untouched (no vmcnt drain).
            asm volatile("s_waitcnt lgkmcnt(0)" ::: "memory");
            __builtin_amdgcn_s_barrier();
        }
    }

    // block top-3 per row via u32 LDS (stride 33); k reconstructed from column
    uint32_t* cl = (uint32_t*)smem;
    u64 g1 = 0, g2 = 0, g3 = 0;
    for (int pass = 0; pass < 2; pass++) {
        __syncthreads();
        #pragma unroll
        for (int s = 0; s < 16; s++) {
            int mi = s >> 2, r = s & 3;
            int row_local = wm * 64 + mi * 16 + q * 4 + r;
            cl[row_local * 33 + wn * 16 + lr] = pass ? v2[s] : v1[s];
        }
        __syncthreads();
        if (t < BT) {
            #pragma unroll 4
            for (int j = 0; j < 32; j++) {
                uint32_t pv = cl[t * 33 + j];
                uint32_t meta = pv & 63u;
                int k = (kslot + (int)(meta >> 2) * KSLOTS) * KT
                      + (j >> 4) * 64 + (int)(meta & 3u) * 16 + (j & 15);
                u64 e = ((u64)(pv & 0xFFFFFFC0u) << 32) | (u64)(~(uint32_t)k);
                u64 t1 = umax64(g1, e), t2 = umin64(g1, e);
                g3 = umax64(g3, umin64(g2, t2));
                g2 = umax64(g2, t2);
                g1 = t1;
            }
        }
    }
    if (t < BT) {
        size_t base = ((size_t)(b0 + t) * KSLOTS + kslot) * 3;
        cand[base] = g1;
        cand[base + 1] = g2;
        cand[base + 2] = g3;
    }
}

// one wave per row: top-8 of 96 candidates, exact fp32 rescore, argmax.
__global__ __launch_bounds__(256) void refine_kernel(
    const float* __restrict__ h, const float* __restrict__ A,
    const float* __restrict__ rn, const u64* __restrict__ cand,
    int* __restrict__ out)
{
    const int t = threadIdx.x, lane = t & 63, wid = t >> 6;
    const int row = blockIdx.x * 4 + wid;
    const u64* cr = cand + (size_t)row * (KSLOTS * 3);
    u64 x0 = cr[lane];                                         // 64 entries
    u64 x1 = (lane < KSLOTS * 3 - 64) ? cr[64 + lane] : 0ULL;  // 32 entries

    u64 sel[8];
    #pragma unroll
    for (int j = 0; j < 8; j++) {
        u64 v = umax64(x0, x1);
        #pragma unroll
        for (int m = 32; m >= 1; m >>= 1) v = umax64(v, __shfl_xor(v, m, 64));
        sel[j] = v;
        if (x0 == v) x0 = 0;
        else if (x1 == v) x1 = 0;
    }

    const fx4* hp = reinterpret_cast<const fx4*>(h + (size_t)row * DIM);
    fx4 h0 = hp[lane * 2], h1 = hp[lane * 2 + 1];

    u64 best = 0;
    #pragma unroll
    for (int j = 0; j < 8; j++) {
        uint32_t kg = ~(uint32_t)sel[j];
        const fx4* ap = reinterpret_cast<const fx4*>(A + (size_t)kg * DIM);
        fx4 a0 = ap[lane * 2], a1 = ap[lane * 2 + 1];
        float s = h0[0]*a0[0] + h0[1]*a0[1] + h0[2]*a0[2] + h0[3]*a0[3]
                + h1[0]*a1[0] + h1[1]*a1[1] + h1[2]*a1[2] + h1[3]*a1[3];
        #pragma unroll
        for (int m = 32; m >= 1; m >>= 1) s += __shfl_xor(s, m, 64);
        s *= rn[kg];
        u64 pk = ((u64)ford(s) << 32) | (u64)(~kg);
        best = umax64(best, pk);
    }
    if (lane == 0) out[row] = (int)(~(uint32_t)best);
}

extern "C" void kernel_launch(void* const* d_in, const int* in_sizes, int n_in,
                              void* d_out, int out_size, void* d_ws, size_t ws_size,
                              hipStream_t stream) {
    const float* h = (const float*)d_in[0];   // [4096, 512]
    const float* A = (const float*)d_in[1];   // [32768, 512]
    int* out = (int*)d_out;                   // [4096] int32

    // ws: a8 (16MB) | h8 (2MB) | rn (128KB) | cand (3MB)
    char* w = (char*)d_ws;
    char* a8 = w;
    char* h8 = w + (size_t)K_ROWS * DIM;
    float* rn = (float*)(w + (size_t)(K_ROWS + B_ROWS) * DIM);
    u64* cand = (u64*)(w + (size_t)(K_ROWS + B_ROWS) * DIM
                         + (size_t)K_ROWS * sizeof(float));

    prep_kernel<<<8192 + 1024, 256, 0, stream>>>(A, h, a8, h8, rn);
    score_kernel<<<32 * KSLOTS, 256, 0, stream>>>(h8, a8, cand);
    refine_kernel<<<B_ROWS / 4, 256, 0, stream>>>(h, A, rn, cand, out);
}